// Round 18
// baseline (2170.111 us; speedup 1.0000x reference)
//
#include <hip/hip_runtime.h>

#define TPB 512
#define SPIN_BOUND (1u << 20)

typedef _Float16 h8 __attribute__((ext_vector_type(8)));
typedef float f4 __attribute__((ext_vector_type(4)));
typedef unsigned long long u64;

__device__ __forceinline__ float sigf(float x) { return 1.f / (1.f + __expf(-x)); }
__device__ __forceinline__ float tanhfast(float x) { return 2.f / (1.f + __expf(-2.f * x)) - 1.f; }

#define MF(acc, a, b) acc = __builtin_amdgcn_mfma_f32_16x16x32_f16(a, b, acc, 0, 0, 0)

__device__ __forceinline__ void vm0() { asm volatile("s_waitcnt vmcnt(0)" ::: "memory"); }
__device__ __forceinline__ void l1inv() { asm volatile("buffer_inv sc0" ::: "memory"); }
__device__ __forceinline__ void lgkm0() { asm volatile("s_waitcnt lgkmcnt(0)" ::: "memory"); }

// PROVEN flag fabric (r7-r9, r14/r15): producer = ONE contiguous 512B burst
// store (block-exclusive lines) + vmcnt(0) + plain flag store; consumer =
// full-line wait, plain-load fast path (flags monotonic), l1inv only while
// spinning, bulk h-load after the single wait.
// r18: (1) flag-per-128B-line (kills producer/consumer false sharing);
//      (2) asymmetric 6/10 h-split (kh0 also runs reduce+gates+publish).
// Do NOT reintroduce: per-chunk interleave (r16 regression), sc0 polls
// (r4/r6/r10 fatal), dedicated poller/LDS broadcast (r11 regression).

// ---------------------------------------------------------------- prep kernels

__global__ void prep_conv(const float* __restrict__ in, const float* __restrict__ mlpw,
                          const float* __restrict__ adpw,
                          _Float16* __restrict__ seqX, _Float16* __restrict__ mlpW16,
                          _Float16* __restrict__ adpW16)
{
    const int NIN = 256 * 128 * 128;
    const int NM = 512 * 512;
    const int NA = 48 * 512;
    int i = blockIdx.x * blockDim.x + threadIdx.x;
    const int stride = gridDim.x * blockDim.x;
    for (; i < NIN + NM + NA; i += stride) {
        if (i < NIN) seqX[i] = (_Float16)in[i];
        else if (i < NIN + NM) mlpW16[i - NIN] = (_Float16)mlpw[i - NIN];
        else adpW16[i - NIN - NM] = (_Float16)adpw[i - NIN - NM];
    }
}

__global__ void prep_bias(const float* __restrict__ a0, const float* __restrict__ b0,
                          const float* __restrict__ a1, const float* __restrict__ b1,
                          const float* __restrict__ a2, const float* __restrict__ b2,
                          const float* __restrict__ a3, const float* __restrict__ b3,
                          float* __restrict__ biasSum)
{
    int i = blockIdx.x * blockDim.x + threadIdx.x;
    if (i >= 8192) return;
    const int c = i >> 11, j = i & 2047;
    const float* A = (c == 0) ? a0 : (c == 1) ? a1 : (c == 2) ? a2 : a3;
    const float* B = (c == 0) ? b0 : (c == 1) ? b1 : (c == 2) ? b2 : b3;
    biasSum[i] = A[j] + B[j];
}

// Wprep layout per cell: [p=32 col-groups][64 rows][K] fp16
__global__ void prep_w(const float* __restrict__ wih0, const float* __restrict__ whh0,
                       const float* __restrict__ wih1, const float* __restrict__ whh1,
                       const float* __restrict__ wih2, const float* __restrict__ whh2,
                       const float* __restrict__ wih3, const float* __restrict__ whh3,
                       _Float16* __restrict__ Wprep)
{
    const size_t N0 = (size_t)2048 * 640;
    const size_t N1 = (size_t)2048 * 1024;
    const size_t total = N0 + 3 * N1;
    size_t i = (size_t)blockIdx.x * blockDim.x + threadIdx.x;
    const size_t stride = (size_t)gridDim.x * blockDim.x;
    for (; i < total; i += stride) {
        int cell; size_t off;
        if (i < N0) { cell = 0; off = i; }
        else { cell = 1 + (int)((i - N0) / N1); off = (i - N0) % N1; }
        const int K = cell ? 1024 : 640;
        const int Din = cell ? 512 : 128;
        const int k = (int)(off % K);
        const int rowIdx = (int)(off / K);
        const int p = rowIdx >> 6;
        const int row64 = rowIdx & 63;
        const int q = row64 >> 4;
        const int gRow = q * 512 + p * 16 + (row64 & 15);
        const float* wih = (cell == 0) ? wih0 : (cell == 1) ? wih1 : (cell == 2) ? wih2 : wih3;
        const float* whh = (cell == 0) ? whh0 : (cell == 1) ? whh1 : (cell == 2) ? whh2 : whh3;
        const float v = (k < Din) ? wih[(size_t)gRow * Din + k]
                                  : whh[(size_t)gRow * 512 + (k - Din)];
        Wprep[i] = (_Float16)v;
    }
}

// ---------------------------------------------------------------- per-cell body

#define SCR_OFF   131072
#define SCRT_OFF  147456
#define MISC_OFF  151552
// flags: cell*65536 + (rg*8+mt)*1024 + p*32 dwords (one 128B line per flag)

#define H_LOAD(arr, HLO, HN_)                                          \
    _Pragma("unroll")                                                  \
    for (int i_ = 0; i_ < (HN_); ++i_)                                 \
        arr[i_] = *(const h8*)(hXp + (size_t)((HLO) + i_) * (Bd * 64));

#define H_MFMA_ALL(arr, HLO, HN_)                                      \
    _Pragma("unroll")                                                  \
    for (int i_ = 0; i_ < (HN_); ++i_) h_mfma(arr[i_], (HLO) + i_, acc);

template<int CELL, int KH, bool XH>
__device__ __forceinline__ void run_cell(
    const _Float16* __restrict__ src, _Float16* __restrict__ dstX,
    const _Float16* __restrict__ wbase, const float* __restrict__ biasSum,
    unsigned* __restrict__ cellFlags, char* smem,
    const int rg, const int p, const int tid, const int lane, const int wave)
{
    constexpr int Din = (CELL == 0) ? 128 : 512;
    constexpr int K = Din + 512;
    constexpr int Bd = 128 << CELL;
    constexpr int PBd = Bd / 2;              // prev cell batch (XH source)
    constexpr int Td = 256 >> CELL;
    constexpr int r = Bd >> 3;
    constexpr int nMt = r >> 4;              // 1,2,4,8
    constexpr int ldsRow = K * 2;
    constexpr int NKX = Din >> 5;            // 4 or 16
    constexpr int NXW = NKX / KH;
    constexpr int NCOMP = nMt * KH;          // 2,4,8,8
    constexpr int HSPL = 6;                  // asymmetric split: kh0=[0,6) kh1=[6,16)

    const int colsel = lane & 15;
    const int kq = lane >> 4;
    const int rowBase = rg * r;

    // stage W slice (64 rows x K fp16) into LDS, XOR-swizzled (all 512 threads)
    {
        const _Float16* wsl = wbase + (size_t)p * 64 * K;
        constexpr int kcN = K >> 3;
        for (int i = tid; i < 64 * kcN; i += TPB) {
            const int row = i / kcN;
            const int kc = i - row * kcN;
            h8 v = *(const h8*)(wsl + (size_t)row * K + (kc << 3));
            *(h8*)(smem + row * ldsRow + ((kc << 4) ^ ((row & 7) << 4))) = v;
        }
    }
    __syncthreads();

    const int mt = wave / KH;
    const int kh = wave % KH;
    const bool busy = (wave < NCOMP);

    const int xlo = kh * NXW;

    const float bq0 = biasSum[CELL * 2048 + 0 * 512 + p * 16 + colsel];
    const float bq1 = biasSum[CELL * 2048 + 1 * 512 + p * 16 + colsel];
    const float bq2 = biasSum[CELL * 2048 + 2 * 512 + p * 16 + colsel];
    const float bq3 = biasSum[CELL * 2048 + 3 * 512 + p * 16 + colsel];

    const int arow = rowBase + mt * 16 + colsel;

    unsigned* line = cellFlags + (rg * 8 + mt) * 1024;   // 32 flags, 128B-strided
    unsigned* myFlag = line + p * 32;
    float* scr = (float*)(smem + SCR_OFF);
    char* scrT = smem + SCRT_OFF + mt * 512;

    float cr[4] = {0.f, 0.f, 0.f, 0.f};
    bool dead = false;
    h8 xr[(NXW > 0) ? NXW : 1];

    // lane-fixed offsets into hX layouts (elements)
    const size_t hOff = (size_t)arow * 16 + (size_t)(kq & 1) * 8 + (size_t)(kq >> 1) * (Bd * 16);
    const int tOff = (arow >= PBd) ? 1 : 0;                       // XH source mapping
    const size_t xBase = (size_t)(arow - tOff * PBd) * 16
                       + (size_t)(kq & 1) * 8 + (size_t)(kq >> 1) * (PBd * 16);

    auto ldB = [&](int kbyte, int rrow) -> h8 {
        return *(const h8*)(smem + rrow * ldsRow + (kbyte ^ ((rrow & 7) << 4)));
    };

    auto wait_line = [&](unsigned tgt) {
        if (dead) return;
        const volatile unsigned* fp = (const volatile unsigned*)(line + (lane & 31) * 32);
        unsigned n = 0;
        for (;;) {
            if (__all((int)(*fp >= tgt))) return;   // plain fast path (monotonic)
            l1inv();
            __builtin_amdgcn_s_sleep(1);
            if (++n > SPIN_BOUND) { dead = true; return; }
        }
    };
    auto wait_own = [&](unsigned tgt) {
        if (dead) return;
        const volatile unsigned* f0 = (const volatile unsigned*)myFlag;
        if (*f0 >= tgt) return;
        unsigned n = 0;
        for (;;) {
            l1inv();
            if (*f0 >= tgt) return;
            __builtin_amdgcn_s_sleep(1);
            if (++n > SPIN_BOUND) { dead = true; return; }
        }
    };

    auto x_issue = [&](int t) {
        if constexpr (XH) {
            const char* xp = (const char*)src
                + ((size_t)(2 * t + tOff) * (32 * PBd * 16) + xBase) * 2;
            #pragma unroll
            for (int i = 0; i < NXW; ++i)
                xr[i] = *(const h8*)(xp + (size_t)(xlo + i) * (PBd * 64));
        } else {
            const _Float16* ap = src + (size_t)t * Bd * Din + (size_t)arow * Din + (kq << 3);
            #pragma unroll
            for (int i = 0; i < NXW; ++i)
                xr[i] = *(const h8*)(ap + ((xlo + i) << 5));
        }
    };
    auto x_compute = [&](f4 (&C)[4]) {
        #pragma unroll
        for (int g = 0; g < 4; ++g) C[g] = (f4){0.f, 0.f, 0.f, 0.f};
        #pragma unroll
        for (int i = 0; i < NXW; ++i) {
            const int kbyte = (((xlo + i) << 5) + (kq << 3)) << 1;
            h8 bf0 = ldB(kbyte, colsel);
            h8 bf1 = ldB(kbyte, 16 + colsel);
            h8 bf2 = ldB(kbyte, 32 + colsel);
            h8 bf3 = ldB(kbyte, 48 + colsel);
            MF(C[0], xr[i], bf0); MF(C[1], xr[i], bf1);
            MF(C[2], xr[i], bf2); MF(C[3], xr[i], bf3);
        }
    };
    auto h_mfma = [&](h8 a, int ks, f4 (&C)[4]) {
        const int kbyte = (Din + (ks << 5) + (kq << 3)) << 1;
        h8 bf0 = ldB(kbyte, colsel);
        h8 bf1 = ldB(kbyte, 16 + colsel);
        h8 bf2 = ldB(kbyte, 32 + colsel);
        h8 bf3 = ldB(kbyte, 48 + colsel);
        MF(C[0], a, bf0); MF(C[1], a, bf1); MF(C[2], a, bf2); MF(C[3], a, bf3);
    };
    auto writeScr = [&](f4 (&C)[4]) {
        const int slot = (mt * (KH - 1) + (kh - 1)) * 4;
        #pragma unroll
        for (int g = 0; g < 4; ++g)
            *(f4*)(scr + (size_t)((slot + g) * 64 + lane) * 4) = C[g];
    };
    auto finish = [&](int t, f4 (&C)[4]) {
        if constexpr (KH > 1) {
            #pragma unroll
            for (int s = 0; s < KH - 1; ++s)
                #pragma unroll
                for (int g = 0; g < 4; ++g)
                    C[g] += *(const f4*)(scr + (size_t)(((mt * (KH - 1) + s) * 4 + g) * 64 + lane) * 4);
        }
        _Float16 hf[4];
        #pragma unroll
        for (int j = 0; j < 4; ++j) {
            const float gi = C[0][j] + bq0;
            const float gf = C[1][j] + bq1;
            const float gg = C[2][j] + bq2;
            const float go = C[3][j] + bq3;
            const float cc = sigf(gf) * cr[j] + sigf(gi) * tanhfast(gg);
            cr[j] = cc;
            hf[j] = (_Float16)(sigf(go) * tanhfast(cc));
        }
        // in-wave LDS transpose -> one contiguous 512B burst per m-tile
        #pragma unroll
        for (int j = 0; j < 4; ++j)
            *(_Float16*)(scrT + (kq * 4 + j) * 32 + colsel * 2) = hf[j];
        lgkm0();
        const u64 v = *(const u64*)(scrT + (lane >> 2) * 32 + (lane & 3) * 8);
        const size_t Ebase = ((size_t)t * 32 + p) * (size_t)(Bd * 16)
                           + (size_t)(rowBase + mt * 16) * 16;
        *(u64*)((char*)dstX + Ebase * 2 + (size_t)lane * 8) = v;
        vm0();                                   // acks exactly this store
        if (lane == 0) *(volatile unsigned*)myFlag = (unsigned)(t + 1);
    };

    f4 acc[4];
    h8 hrA[8];
    h8 hrB[8];
    if (busy) x_issue(0);

    for (int t = 0; t < Td; ++t) {
        const char* hXp = (const char*)dstX + ((size_t)(t - 1) * (32 * Bd * 16) + hOff) * 2;
        if (busy) {
            if (t == 0) {
                x_compute(acc);
            } else if constexpr (KH == 1) {
                wait_line((unsigned)t);
                H_LOAD(hrA, 0, 8)
                x_compute(acc);
                H_LOAD(hrB, 8, 8)
                H_MFMA_ALL(hrA, 0, 8)
                H_MFMA_ALL(hrB, 8, 8)
            } else {
                if (kh == 0) {
                    wait_line((unsigned)t);
                    H_LOAD(hrA, 0, HSPL)
                    x_compute(acc);
                    H_MFMA_ALL(hrA, 0, HSPL)
                } else {
                    wait_own((unsigned)t);       // scratch free: finish(t-1) done
                    wait_line((unsigned)t);
                    H_LOAD(hrA, HSPL, 8)
                    x_compute(acc);
                    H_LOAD(hrB, HSPL + 8, 16 - HSPL - 8)
                    H_MFMA_ALL(hrA, HSPL, 8)
                    H_MFMA_ALL(hrB, HSPL + 8, 16 - HSPL - 8)
                }
            }
        }
        if constexpr (KH > 1) {
            if (busy && kh != 0) writeScr(acc);
            __syncthreads();
        }
        if (busy && kh == 0) finish(t, acc);
        if (busy && t + 1 < Td) x_issue(t + 1);
    }
    vm0();
}

// ---------------------------------------------------------------- persistent kernel

__global__ __launch_bounds__(TPB) void drnn_persist(
    const _Float16* __restrict__ seqX,
    _Float16* __restrict__ seq0X,
    _Float16* __restrict__ seq1X,
    _Float16* __restrict__ seq2X,
    _Float16* __restrict__ seq3X,
    const _Float16* __restrict__ Wprep,
    const float* __restrict__ biasSum,
    unsigned* __restrict__ syncc)
{
    extern __shared__ char smem[];
    const int tid = threadIdx.x;
    const int lane = tid & 63;
    const int wave = tid >> 6;

    unsigned* s_misc = (unsigned*)(smem + MISC_OFF);

    // XCD self-assign: rg == physical XCD; ~148KB LDS -> 1 block/CU -> 32/XCD.
    if (tid == 0) {
        unsigned xcc;
        asm volatile("s_getreg_b32 %0, hwreg(HW_REG_XCC_ID)" : "=s"(xcc));
        xcc &= 7u;
        unsigned slot = __hip_atomic_fetch_add(syncc + 512u + 64u * xcc, 1u,
                                               __ATOMIC_RELAXED, __HIP_MEMORY_SCOPE_AGENT);
        s_misc[0] = (xcc << 5) | (slot & 31u);
    }
    __syncthreads();
    const unsigned rgp = s_misc[0];
    __syncthreads();
    const int rg = rgp >> 5;
    const int p = rgp & 31;

    unsigned* cellCnt = syncc;               // dword 0
    unsigned* flags = syncc + 4096;          // cell*65536 + (rg*8+mt)*1024 + p*32

    auto cell_barrier = [&](int cellIdx, unsigned TdPrev, int nMtPrev, unsigned* flagsPrev) {
        __syncthreads();
        if (p == 0 && tid < 32 * nMtPrev) {
            const volatile unsigned* fp =
                (const volatile unsigned*)(flagsPrev + (rg * 8 + (tid >> 5)) * 1024 + (tid & 31) * 32);
            unsigned n = 0;
            for (;;) {
                l1inv();
                if (*fp >= TdPrev) break;
                __builtin_amdgcn_s_sleep(1);
                if (++n > SPIN_BOUND) break;
            }
        }
        __syncthreads();
        if (tid == 0) {
            if (p == 0)
                __hip_atomic_fetch_add(cellCnt, 1u, __ATOMIC_RELEASE, __HIP_MEMORY_SCOPE_AGENT);
            unsigned n = 0;
            while (__hip_atomic_load(cellCnt, __ATOMIC_RELAXED, __HIP_MEMORY_SCOPE_AGENT)
                   < (unsigned)(8 * cellIdx)) {
                __builtin_amdgcn_s_sleep(1);
                if (++n > SPIN_BOUND) break;
            }
            (void)__hip_atomic_load(cellCnt, __ATOMIC_ACQUIRE, __HIP_MEMORY_SCOPE_AGENT);
        }
        __syncthreads();
        l1inv();
    };

    run_cell<0, 2, false>(seqX,  seq0X, Wprep,                        biasSum, flags + 0 * 65536, smem, rg, p, tid, lane, wave);
    cell_barrier(1, 256u, 1, flags + 0 * 65536);
    run_cell<1, 2, true >(seq0X, seq1X, Wprep + (size_t)2048 * 640,   biasSum, flags + 1 * 65536, smem, rg, p, tid, lane, wave);
    cell_barrier(2, 128u, 2, flags + 1 * 65536);
    run_cell<2, 2, true >(seq1X, seq2X, Wprep + (size_t)2048 * 1664,  biasSum, flags + 2 * 65536, smem, rg, p, tid, lane, wave);
    cell_barrier(3, 64u, 4, flags + 2 * 65536);
    run_cell<3, 1, true >(seq2X, seq3X, Wprep + (size_t)2048 * 2688,  biasSum, flags + 3 * 65536, smem, rg, p, tid, lane, wave);
}

// ---------------------------------------------------------------- head
// seq1/seq3 read from hX layouts:
// cell1 (Bd=256): elem ((R>>8)*32 + k/16)*4096  + (R&255)*16  + k%16
// cell3 (Bd=1024): elem ((R>>10)*32 + k/16)*16384 + (R&1023)*16 + k%16

__global__ __launch_bounds__(256) void head_kernel(
    const _Float16* __restrict__ seq1X,
    const _Float16* __restrict__ seq3X,
    const _Float16* __restrict__ mlpW16,
    const float* __restrict__ mlp_b,
    const _Float16* __restrict__ adpW16,
    const float* __restrict__ adp_b,
    float* __restrict__ out)
{
    extern __shared__ char smem[];   // y1 tile [64][512] fp16, XOR-swizzled
    const int tid = threadIdx.x;
    const int lane = tid & 63, wave = tid >> 6;
    const int colsel = lane & 15, kq = lane >> 4;
    const size_t row0 = (size_t)blockIdx.x * 64 + wave * 16;

    h8 aR[16];
    {
        const size_t R = row0 + colsel;
        const size_t off1 = ((R >> 8) * 32 + (size_t)(kq >> 1)) * 4096
                          + (R & 255) * 16 + (size_t)(kq & 1) * 8;
        const size_t off3 = ((R >> 10) * 32 + (size_t)(kq >> 1)) * 16384
                          + (R & 1023) * 16 + (size_t)(kq & 1) * 8;
        #pragma unroll
        for (int ks = 0; ks < 16; ++ks) {
            h8 a1 = *(const h8*)(seq1X + off1 + (size_t)ks * 8192);
            h8 a3 = *(const h8*)(seq3X + off3 + (size_t)ks * 32768);
            aR[ks] = a1 + a3;
        }
    }
    for (int nt = 0; nt < 32; ++nt) {
        f4 acc = {0.f, 0.f, 0.f, 0.f};
        const int brow = nt * 16 + colsel;
        #pragma unroll
        for (int ks = 0; ks < 16; ++ks) {
            const int kb = ks * 32 + kq * 8;
            h8 b = *(const h8*)(mlpW16 + (size_t)brow * 512 + kb);
            acc = __builtin_amdgcn_mfma_f32_16x16x32_f16(aR[ks], b, acc, 0, 0, 0);
        }
        const int n = nt * 16 + colsel;
        const float bn = mlp_b[n];
        const int lrow0 = wave * 16 + kq * 4;
        #pragma unroll
        for (int j = 0; j < 4; ++j) {
            const float y = tanhfast(acc[j] + bn);
            const int row = lrow0 + j;
            *(_Float16*)(smem + row * 1024 + ((n * 2) ^ ((row & 7) << 4))) = (_Float16)y;
        }
    }
    __syncthreads();
    f4 acc0 = {0.f,0.f,0.f,0.f}, acc1 = {0.f,0.f,0.f,0.f}, acc2 = {0.f,0.f,0.f,0.f};
    const int arow = wave * 16 + colsel;
    #pragma unroll
    for (int ks = 0; ks < 16; ++ks) {
        const int kb = ks * 32 + kq * 8;
        h8 a = *(const h8*)(smem + arow * 1024 + ((kb * 2) ^ ((arow & 7) << 4)));
        h8 b0 = *(const h8*)(adpW16 + (size_t)(colsel) * 512 + kb);
        h8 b1 = *(const h8*)(adpW16 + (size_t)(16 + colsel) * 512 + kb);
        h8 b2 = *(const h8*)(adpW16 + (size_t)(32 + colsel) * 512 + kb);
        acc0 = __builtin_amdgcn_mfma_f32_16x16x32_f16(a, b0, acc0, 0, 0, 0);
        acc1 = __builtin_amdgcn_mfma_f32_16x16x32_f16(a, b1, acc1, 0, 0, 0);
        acc2 = __builtin_amdgcn_mfma_f32_16x16x32_f16(a, b2, acc2, 0, 0, 0);
    }
    const size_t orow0 = row0 + kq * 4;
    #pragma unroll
    for (int j = 0; j < 4; ++j) {
        out[(orow0 + j) * 48 + colsel]      = acc0[j] + adp_b[colsel];
        out[(orow0 + j) * 48 + 16 + colsel] = acc1[j] + adp_b[16 + colsel];
        out[(orow0 + j) * 48 + 32 + colsel] = acc2[j] + adp_b[32 + colsel];
    }
}

// ---------------------------------------------------------------- launch

extern "C" void kernel_launch(void* const* d_in, const int* in_sizes, int n_in,
                              void* d_out, int out_size, void* d_ws, size_t ws_size,
                              hipStream_t stream)
{
    (void)in_sizes; (void)n_in; (void)out_size; (void)ws_size;
    const float* input = (const float*)d_in[0];
    const float* Wih[4]; const float* Whh[4]; const float* Bih[4]; const float* Bhh[4];
    for (int i = 0; i < 4; ++i) {
        Wih[i] = (const float*)d_in[1 + 4 * i];
        Whh[i] = (const float*)d_in[2 + 4 * i];
        Bih[i] = (const float*)d_in[3 + 4 * i];
        Bhh[i] = (const float*)d_in[4 + 4 * i];
    }
    const float* mlpw = (const float*)d_in[17];
    const float* mlpb = (const float*)d_in[18];
    const float* adpw = (const float*)d_in[19];
    const float* adpb = (const float*)d_in[20];
    float* out = (float*)d_out;

    char* ws = (char*)d_ws;
    size_t off = 0;
    auto alloc = [&](size_t bytes) -> char* {
        char* ptr = ws + off;
        off += (bytes + 255) & ~(size_t)255;
        return ptr;
    };
    const size_t SEQB = (size_t)32768 * 512 * 2;   // 33.5 MB per hX buffer
    const size_t SYNC_BYTES = (size_t)(4096 + 4 * 65536) * 4;   // ~1.06 MB
    unsigned* syncc   = (unsigned*)alloc(SYNC_BYTES);
    _Float16* seqX    = (_Float16*)alloc((size_t)32768 * 128 * 2);
    _Float16* seq0X   = (_Float16*)alloc(SEQB);
    _Float16* seq1X   = (_Float16*)alloc(SEQB);
    _Float16* seq2X   = (_Float16*)alloc(SEQB);
    _Float16* seq3X   = (_Float16*)alloc(SEQB);
    _Float16* Wprep   = (_Float16*)alloc((size_t)2048 * 3712 * 2);
    float*    biasSum = (float*)alloc(8192 * 4);
    _Float16* mlpW16  = (_Float16*)alloc((size_t)262144 * 2);
    _Float16* adpW16  = (_Float16*)alloc((size_t)24576 * 2);

    hipMemsetAsync(syncc, 0, SYNC_BYTES, stream);
    prep_conv<<<2048, 256, 0, stream>>>(input, mlpw, adpw, seqX, mlpW16, adpW16);
    prep_bias<<<32, 256, 0, stream>>>(Bih[0], Bhh[0], Bih[1], Bhh[1],
                                      Bih[2], Bhh[2], Bih[3], Bhh[3], biasSum);
    prep_w<<<4096, 256, 0, stream>>>(Wih[0], Whh[0], Wih[1], Whh[1],
                                     Wih[2], Whh[2], Wih[3], Whh[3], Wprep);

    const int ldsBytes = MISC_OFF + 128;   // 151,680
    hipFuncSetAttribute((const void*)drnn_persist,
                        hipFuncAttributeMaxDynamicSharedMemorySize, ldsBytes);
    hipFuncSetAttribute((const void*)head_kernel,
                        hipFuncAttributeMaxDynamicSharedMemorySize, 65536);

    drnn_persist<<<256, TPB, ldsBytes, stream>>>(seqX, seq0X, seq1X, seq2X, seq3X,
                                                 Wprep, biasSum, syncc);
    head_kernel<<<512, 256, 65536, stream>>>(seq1X, seq3X, mlpW16, mlpb, adpW16, adpb, out);
}

// Round 19
// 2001.664 us; speedup vs baseline: 1.0842x; 1.0842x over previous
//
#include <hip/hip_runtime.h>

#define TPB 512
#define SPIN_BOUND (1u << 20)

typedef _Float16 h8 __attribute__((ext_vector_type(8)));
typedef float f4 __attribute__((ext_vector_type(4)));
typedef unsigned long long u64;

__device__ __forceinline__ float sigf(float x) { return 1.f / (1.f + __expf(-x)); }
__device__ __forceinline__ float tanhfast(float x) { return 2.f / (1.f + __expf(-2.f * x)) - 1.f; }

#define MF(acc, a, b) acc = __builtin_amdgcn_mfma_f32_16x16x32_f16(a, b, acc, 0, 0, 0)

__device__ __forceinline__ void vm0() { asm volatile("s_waitcnt vmcnt(0)" ::: "memory"); }
__device__ __forceinline__ void l1inv() { asm volatile("buffer_inv sc0" ::: "memory"); }
__device__ __forceinline__ void lgkm0() { asm volatile("s_waitcnt lgkmcnt(0)" ::: "memory"); }

// FINAL (r19 = r15, best-known): producer = ONE contiguous 512B burst store
// (block-exclusive lines) + vmcnt(0) (acks exactly that store) + plain flag
// store (write-through L1 -> shared XCD L2); consumer = full-line wait with
// plain-load fast path (flags monotonic), l1inv only while spinning, bulk
// h-load after the single wait. All h consumers read the hX burst layout.
// Falsified refinements (do not reintroduce): per-chunk interleave (r16 -20%),
// x_compute hoist (r17 null), 128B flag stride + 6/10 split (r18 -8%),
// sc0 polls (r4/r6/r10 fatal), dedicated poller (r11), per-cell kernels (r10/11).

// ---------------------------------------------------------------- prep kernels

__global__ void prep_conv(const float* __restrict__ in, const float* __restrict__ mlpw,
                          const float* __restrict__ adpw,
                          _Float16* __restrict__ seqX, _Float16* __restrict__ mlpW16,
                          _Float16* __restrict__ adpW16)
{
    const int NIN = 256 * 128 * 128;
    const int NM = 512 * 512;
    const int NA = 48 * 512;
    int i = blockIdx.x * blockDim.x + threadIdx.x;
    const int stride = gridDim.x * blockDim.x;
    for (; i < NIN + NM + NA; i += stride) {
        if (i < NIN) seqX[i] = (_Float16)in[i];
        else if (i < NIN + NM) mlpW16[i - NIN] = (_Float16)mlpw[i - NIN];
        else adpW16[i - NIN - NM] = (_Float16)adpw[i - NIN - NM];
    }
}

__global__ void prep_bias(const float* __restrict__ a0, const float* __restrict__ b0,
                          const float* __restrict__ a1, const float* __restrict__ b1,
                          const float* __restrict__ a2, const float* __restrict__ b2,
                          const float* __restrict__ a3, const float* __restrict__ b3,
                          float* __restrict__ biasSum)
{
    int i = blockIdx.x * blockDim.x + threadIdx.x;
    if (i >= 8192) return;
    const int c = i >> 11, j = i & 2047;
    const float* A = (c == 0) ? a0 : (c == 1) ? a1 : (c == 2) ? a2 : a3;
    const float* B = (c == 0) ? b0 : (c == 1) ? b1 : (c == 2) ? b2 : b3;
    biasSum[i] = A[j] + B[j];
}

// Wprep layout per cell: [p=32 col-groups][64 rows][K] fp16
__global__ void prep_w(const float* __restrict__ wih0, const float* __restrict__ whh0,
                       const float* __restrict__ wih1, const float* __restrict__ whh1,
                       const float* __restrict__ wih2, const float* __restrict__ whh2,
                       const float* __restrict__ wih3, const float* __restrict__ whh3,
                       _Float16* __restrict__ Wprep)
{
    const size_t N0 = (size_t)2048 * 640;
    const size_t N1 = (size_t)2048 * 1024;
    const size_t total = N0 + 3 * N1;
    size_t i = (size_t)blockIdx.x * blockDim.x + threadIdx.x;
    const size_t stride = (size_t)gridDim.x * blockDim.x;
    for (; i < total; i += stride) {
        int cell; size_t off;
        if (i < N0) { cell = 0; off = i; }
        else { cell = 1 + (int)((i - N0) / N1); off = (i - N0) % N1; }
        const int K = cell ? 1024 : 640;
        const int Din = cell ? 512 : 128;
        const int k = (int)(off % K);
        const int rowIdx = (int)(off / K);
        const int p = rowIdx >> 6;
        const int row64 = rowIdx & 63;
        const int q = row64 >> 4;
        const int gRow = q * 512 + p * 16 + (row64 & 15);
        const float* wih = (cell == 0) ? wih0 : (cell == 1) ? wih1 : (cell == 2) ? wih2 : wih3;
        const float* whh = (cell == 0) ? whh0 : (cell == 1) ? whh1 : (cell == 2) ? whh2 : whh3;
        const float v = (k < Din) ? wih[(size_t)gRow * Din + k]
                                  : whh[(size_t)gRow * 512 + (k - Din)];
        Wprep[i] = (_Float16)v;
    }
}

// ---------------------------------------------------------------- per-cell body

#define SCR_OFF   131072
#define SCRT_OFF  147456
#define MISC_OFF  151552

template<int CELL, int KH, bool XH>
__device__ __forceinline__ void run_cell(
    const _Float16* __restrict__ src, _Float16* __restrict__ dstX,
    const _Float16* __restrict__ wbase, const float* __restrict__ biasSum,
    unsigned* __restrict__ cellFlags, char* smem,
    const int rg, const int p, const int tid, const int lane, const int wave)
{
    constexpr int Din = (CELL == 0) ? 128 : 512;
    constexpr int K = Din + 512;
    constexpr int Bd = 128 << CELL;
    constexpr int PBd = Bd / 2;              // prev cell batch (XH source)
    constexpr int Td = 256 >> CELL;
    constexpr int r = Bd >> 3;
    constexpr int nMt = r >> 4;              // 1,2,4,8
    constexpr int ldsRow = K * 2;
    constexpr int NKX = Din >> 5;            // 4 or 16
    constexpr int NXW = NKX / KH;
    constexpr int NHW = 16 / KH;             // h chunks per wave
    constexpr int B1 = (NHW > 8) ? 8 : NHW;
    constexpr int B2 = NHW - B1;
    constexpr int NCOMP = nMt * KH;          // 2,4,8,8

    const int colsel = lane & 15;
    const int kq = lane >> 4;
    const int rowBase = rg * r;

    // stage W slice (64 rows x K fp16) into LDS, XOR-swizzled (all 512 threads)
    {
        const _Float16* wsl = wbase + (size_t)p * 64 * K;
        constexpr int kcN = K >> 3;
        for (int i = tid; i < 64 * kcN; i += TPB) {
            const int row = i / kcN;
            const int kc = i - row * kcN;
            h8 v = *(const h8*)(wsl + (size_t)row * K + (kc << 3));
            *(h8*)(smem + row * ldsRow + ((kc << 4) ^ ((row & 7) << 4))) = v;
        }
    }
    __syncthreads();

    const int mt = wave / KH;
    const int kh = wave % KH;
    const bool busy = (wave < NCOMP);

    const int xlo = kh * NXW;
    const int hlo = kh * NHW;

    const float bq0 = biasSum[CELL * 2048 + 0 * 512 + p * 16 + colsel];
    const float bq1 = biasSum[CELL * 2048 + 1 * 512 + p * 16 + colsel];
    const float bq2 = biasSum[CELL * 2048 + 2 * 512 + p * 16 + colsel];
    const float bq3 = biasSum[CELL * 2048 + 3 * 512 + p * 16 + colsel];

    const int arow = rowBase + mt * 16 + colsel;

    unsigned* line = cellFlags + (rg * 8 + mt) * 256;   // 32 flags, 32B-strided
    unsigned* myFlag = line + p * 8;
    float* scr = (float*)(smem + SCR_OFF);
    char* scrT = smem + SCRT_OFF + mt * 512;

    float cr[4] = {0.f, 0.f, 0.f, 0.f};
    bool dead = false;
    h8 xr[(NXW > 0) ? NXW : 1];

    // lane-fixed offsets into hX layouts (elements)
    const size_t hOff = (size_t)arow * 16 + (size_t)(kq & 1) * 8 + (size_t)(kq >> 1) * (Bd * 16);
    const int tOff = (arow >= PBd) ? 1 : 0;                       // XH source mapping
    const size_t xBase = (size_t)(arow - tOff * PBd) * 16
                       + (size_t)(kq & 1) * 8 + (size_t)(kq >> 1) * (PBd * 16);

    auto ldB = [&](int kbyte, int rrow) -> h8 {
        return *(const h8*)(smem + rrow * ldsRow + (kbyte ^ ((rrow & 7) << 4)));
    };

    auto wait_line = [&](unsigned tgt) {
        if (dead) return;
        const volatile unsigned* fp = (const volatile unsigned*)(line + (lane & 31) * 8);
        unsigned n = 0;
        for (;;) {
            if (__all((int)(*fp >= tgt))) return;   // plain fast path (monotonic)
            l1inv();
            __builtin_amdgcn_s_sleep(1);
            if (++n > SPIN_BOUND) { dead = true; return; }
        }
    };
    auto wait_own = [&](unsigned tgt) {
        if (dead) return;
        const volatile unsigned* f0 = (const volatile unsigned*)myFlag;
        if (*f0 >= tgt) return;
        unsigned n = 0;
        for (;;) {
            l1inv();
            if (*f0 >= tgt) return;
            __builtin_amdgcn_s_sleep(1);
            if (++n > SPIN_BOUND) { dead = true; return; }
        }
    };

    auto x_issue = [&](int t) {
        if constexpr (XH) {
            const char* xp = (const char*)src
                + ((size_t)(2 * t + tOff) * (32 * PBd * 16) + xBase) * 2;
            #pragma unroll
            for (int i = 0; i < NXW; ++i)
                xr[i] = *(const h8*)(xp + (size_t)(xlo + i) * (PBd * 64));
        } else {
            const _Float16* ap = src + (size_t)t * Bd * Din + (size_t)arow * Din + (kq << 3);
            #pragma unroll
            for (int i = 0; i < NXW; ++i)
                xr[i] = *(const h8*)(ap + ((xlo + i) << 5));
        }
    };
    auto x_compute = [&](f4 (&C)[4]) {
        #pragma unroll
        for (int g = 0; g < 4; ++g) C[g] = (f4){0.f, 0.f, 0.f, 0.f};
        #pragma unroll
        for (int i = 0; i < NXW; ++i) {
            const int kbyte = (((xlo + i) << 5) + (kq << 3)) << 1;
            h8 bf0 = ldB(kbyte, colsel);
            h8 bf1 = ldB(kbyte, 16 + colsel);
            h8 bf2 = ldB(kbyte, 32 + colsel);
            h8 bf3 = ldB(kbyte, 48 + colsel);
            MF(C[0], xr[i], bf0); MF(C[1], xr[i], bf1);
            MF(C[2], xr[i], bf2); MF(C[3], xr[i], bf3);
        }
    };
    auto h_mfma = [&](h8 a, int ks, f4 (&C)[4]) {
        const int kbyte = (Din + (ks << 5) + (kq << 3)) << 1;
        h8 bf0 = ldB(kbyte, colsel);
        h8 bf1 = ldB(kbyte, 16 + colsel);
        h8 bf2 = ldB(kbyte, 32 + colsel);
        h8 bf3 = ldB(kbyte, 48 + colsel);
        MF(C[0], a, bf0); MF(C[1], a, bf1); MF(C[2], a, bf2); MF(C[3], a, bf3);
    };
    auto writeScr = [&](f4 (&C)[4]) {
        const int slot = (mt * (KH - 1) + (kh - 1)) * 4;
        #pragma unroll
        for (int g = 0; g < 4; ++g)
            *(f4*)(scr + (size_t)((slot + g) * 64 + lane) * 4) = C[g];
    };
    auto finish = [&](int t, f4 (&C)[4]) {
        if constexpr (KH > 1) {
            #pragma unroll
            for (int s = 0; s < KH - 1; ++s)
                #pragma unroll
                for (int g = 0; g < 4; ++g)
                    C[g] += *(const f4*)(scr + (size_t)(((mt * (KH - 1) + s) * 4 + g) * 64 + lane) * 4);
        }
        _Float16 hf[4];
        #pragma unroll
        for (int j = 0; j < 4; ++j) {
            const float gi = C[0][j] + bq0;
            const float gf = C[1][j] + bq1;
            const float gg = C[2][j] + bq2;
            const float go = C[3][j] + bq3;
            const float cc = sigf(gf) * cr[j] + sigf(gi) * tanhfast(gg);
            cr[j] = cc;
            hf[j] = (_Float16)(sigf(go) * tanhfast(cc));
        }
        // in-wave LDS transpose -> one contiguous 512B burst per m-tile
        #pragma unroll
        for (int j = 0; j < 4; ++j)
            *(_Float16*)(scrT + (kq * 4 + j) * 32 + colsel * 2) = hf[j];
        lgkm0();
        const u64 v = *(const u64*)(scrT + (lane >> 2) * 32 + (lane & 3) * 8);
        const size_t Ebase = ((size_t)t * 32 + p) * (size_t)(Bd * 16)
                           + (size_t)(rowBase + mt * 16) * 16;
        *(u64*)((char*)dstX + Ebase * 2 + (size_t)lane * 8) = v;
        vm0();                                   // acks exactly this store
        if (lane == 0) *(volatile unsigned*)myFlag = (unsigned)(t + 1);
    };

    f4 acc[4];
    h8 hrA[B1];
    h8 hrB[(B2 > 0) ? B2 : 1];
    if (busy) x_issue(0);

    for (int t = 0; t < Td; ++t) {
        const char* hXp = (const char*)dstX + ((size_t)(t - 1) * (32 * Bd * 16) + hOff) * 2;
        if (busy && t > 0) {
            if constexpr (KH > 1) { if (kh != 0) wait_own((unsigned)t); }
            wait_line((unsigned)t);
            #pragma unroll
            for (int i = 0; i < B1; ++i)
                hrA[i] = *(const h8*)(hXp + (size_t)(hlo + i) * (Bd * 64));
        }
        if (busy) {
            x_compute(acc);                     // hides h-load latency
            if (t > 0) {
                if constexpr (B2 > 0) {
                    #pragma unroll
                    for (int i = 0; i < B2; ++i)
                        hrB[i] = *(const h8*)(hXp + (size_t)(hlo + B1 + i) * (Bd * 64));
                }
                #pragma unroll
                for (int i = 0; i < B1; ++i) h_mfma(hrA[i], hlo + i, acc);
                if constexpr (B2 > 0) {
                    #pragma unroll
                    for (int i = 0; i < B2; ++i) h_mfma(hrB[i], hlo + B1 + i, acc);
                }
            }
        }
        if constexpr (KH > 1) {
            if (busy && kh != 0) writeScr(acc);
            __syncthreads();
        }
        if (busy && kh == 0) finish(t, acc);
        if (busy && t + 1 < Td) x_issue(t + 1);
    }
    vm0();
}

// ---------------------------------------------------------------- persistent kernel

__global__ __launch_bounds__(TPB) void drnn_persist(
    const _Float16* __restrict__ seqX,
    _Float16* __restrict__ seq0X,
    _Float16* __restrict__ seq1X,
    _Float16* __restrict__ seq2X,
    _Float16* __restrict__ seq3X,
    const _Float16* __restrict__ Wprep,
    const float* __restrict__ biasSum,
    unsigned* __restrict__ syncc)
{
    extern __shared__ char smem[];
    const int tid = threadIdx.x;
    const int lane = tid & 63;
    const int wave = tid >> 6;

    unsigned* s_misc = (unsigned*)(smem + MISC_OFF);

    // XCD self-assign: rg == physical XCD; ~148KB LDS -> 1 block/CU -> 32/XCD.
    if (tid == 0) {
        unsigned xcc;
        asm volatile("s_getreg_b32 %0, hwreg(HW_REG_XCC_ID)" : "=s"(xcc));
        xcc &= 7u;
        unsigned slot = __hip_atomic_fetch_add(syncc + 512u + 64u * xcc, 1u,
                                               __ATOMIC_RELAXED, __HIP_MEMORY_SCOPE_AGENT);
        s_misc[0] = (xcc << 5) | (slot & 31u);
    }
    __syncthreads();
    const unsigned rgp = s_misc[0];
    __syncthreads();
    const int rg = rgp >> 5;
    const int p = rgp & 31;

    unsigned* cellCnt = syncc;               // dword 0
    unsigned* flags = syncc + 4096;          // cell*16384 + (rg*8+mt)*256 + p*8

    auto cell_barrier = [&](int cellIdx, unsigned TdPrev, int nMtPrev, unsigned* flagsPrev) {
        __syncthreads();
        if (p == 0 && tid < 32 * nMtPrev) {
            const volatile unsigned* fp =
                (const volatile unsigned*)(flagsPrev + (rg * 8 + (tid >> 5)) * 256 + (tid & 31) * 8);
            unsigned n = 0;
            for (;;) {
                l1inv();
                if (*fp >= TdPrev) break;
                __builtin_amdgcn_s_sleep(1);
                if (++n > SPIN_BOUND) break;
            }
        }
        __syncthreads();
        if (tid == 0) {
            if (p == 0)
                __hip_atomic_fetch_add(cellCnt, 1u, __ATOMIC_RELEASE, __HIP_MEMORY_SCOPE_AGENT);
            unsigned n = 0;
            while (__hip_atomic_load(cellCnt, __ATOMIC_RELAXED, __HIP_MEMORY_SCOPE_AGENT)
                   < (unsigned)(8 * cellIdx)) {
                __builtin_amdgcn_s_sleep(1);
                if (++n > SPIN_BOUND) break;
            }
            (void)__hip_atomic_load(cellCnt, __ATOMIC_ACQUIRE, __HIP_MEMORY_SCOPE_AGENT);
        }
        __syncthreads();
        l1inv();
    };

    run_cell<0, 2, false>(seqX,  seq0X, Wprep,                        biasSum, flags + 0 * 16384, smem, rg, p, tid, lane, wave);
    cell_barrier(1, 256u, 1, flags + 0 * 16384);
    run_cell<1, 2, true >(seq0X, seq1X, Wprep + (size_t)2048 * 640,   biasSum, flags + 1 * 16384, smem, rg, p, tid, lane, wave);
    cell_barrier(2, 128u, 2, flags + 1 * 16384);
    run_cell<2, 2, true >(seq1X, seq2X, Wprep + (size_t)2048 * 1664,  biasSum, flags + 2 * 16384, smem, rg, p, tid, lane, wave);
    cell_barrier(3, 64u, 4, flags + 2 * 16384);
    run_cell<3, 1, true >(seq2X, seq3X, Wprep + (size_t)2048 * 2688,  biasSum, flags + 3 * 16384, smem, rg, p, tid, lane, wave);
}

// ---------------------------------------------------------------- head
// seq1/seq3 read from hX layouts:
// cell1 (Bd=256): elem ((R>>8)*32 + k/16)*4096  + (R&255)*16  + k%16
// cell3 (Bd=1024): elem ((R>>10)*32 + k/16)*16384 + (R&1023)*16 + k%16

__global__ __launch_bounds__(256) void head_kernel(
    const _Float16* __restrict__ seq1X,
    const _Float16* __restrict__ seq3X,
    const _Float16* __restrict__ mlpW16,
    const float* __restrict__ mlp_b,
    const _Float16* __restrict__ adpW16,
    const float* __restrict__ adp_b,
    float* __restrict__ out)
{
    extern __shared__ char smem[];   // y1 tile [64][512] fp16, XOR-swizzled
    const int tid = threadIdx.x;
    const int lane = tid & 63, wave = tid >> 6;
    const int colsel = lane & 15, kq = lane >> 4;
    const size_t row0 = (size_t)blockIdx.x * 64 + wave * 16;

    h8 aR[16];
    {
        const size_t R = row0 + colsel;
        const size_t off1 = ((R >> 8) * 32 + (size_t)(kq >> 1)) * 4096
                          + (R & 255) * 16 + (size_t)(kq & 1) * 8;
        const size_t off3 = ((R >> 10) * 32 + (size_t)(kq >> 1)) * 16384
                          + (R & 1023) * 16 + (size_t)(kq & 1) * 8;
        #pragma unroll
        for (int ks = 0; ks < 16; ++ks) {
            h8 a1 = *(const h8*)(seq1X + off1 + (size_t)ks * 8192);
            h8 a3 = *(const h8*)(seq3X + off3 + (size_t)ks * 32768);
            aR[ks] = a1 + a3;
        }
    }
    for (int nt = 0; nt < 32; ++nt) {
        f4 acc = {0.f, 0.f, 0.f, 0.f};
        const int brow = nt * 16 + colsel;
        #pragma unroll
        for (int ks = 0; ks < 16; ++ks) {
            const int kb = ks * 32 + kq * 8;
            h8 b = *(const h8*)(mlpW16 + (size_t)brow * 512 + kb);
            acc = __builtin_amdgcn_mfma_f32_16x16x32_f16(aR[ks], b, acc, 0, 0, 0);
        }
        const int n = nt * 16 + colsel;
        const float bn = mlp_b[n];
        const int lrow0 = wave * 16 + kq * 4;
        #pragma unroll
        for (int j = 0; j < 4; ++j) {
            const float y = tanhfast(acc[j] + bn);
            const int row = lrow0 + j;
            *(_Float16*)(smem + row * 1024 + ((n * 2) ^ ((row & 7) << 4))) = (_Float16)y;
        }
    }
    __syncthreads();
    f4 acc0 = {0.f,0.f,0.f,0.f}, acc1 = {0.f,0.f,0.f,0.f}, acc2 = {0.f,0.f,0.f,0.f};
    const int arow = wave * 16 + colsel;
    #pragma unroll
    for (int ks = 0; ks < 16; ++ks) {
        const int kb = ks * 32 + kq * 8;
        h8 a = *(const h8*)(smem + arow * 1024 + ((kb * 2) ^ ((arow & 7) << 4)));
        h8 b0 = *(const h8*)(adpW16 + (size_t)(colsel) * 512 + kb);
        h8 b1 = *(const h8*)(adpW16 + (size_t)(16 + colsel) * 512 + kb);
        h8 b2 = *(const h8*)(adpW16 + (size_t)(32 + colsel) * 512 + kb);
        acc0 = __builtin_amdgcn_mfma_f32_16x16x32_f16(a, b0, acc0, 0, 0, 0);
        acc1 = __builtin_amdgcn_mfma_f32_16x16x32_f16(a, b1, acc1, 0, 0, 0);
        acc2 = __builtin_amdgcn_mfma_f32_16x16x32_f16(a, b2, acc2, 0, 0, 0);
    }
    const size_t orow0 = row0 + kq * 4;
    #pragma unroll
    for (int j = 0; j < 4; ++j) {
        out[(orow0 + j) * 48 + colsel]      = acc0[j] + adp_b[colsel];
        out[(orow0 + j) * 48 + 16 + colsel] = acc1[j] + adp_b[16 + colsel];
        out[(orow0 + j) * 48 + 32 + colsel] = acc2[j] + adp_b[32 + colsel];
    }
}

// ---------------------------------------------------------------- launch

extern "C" void kernel_launch(void* const* d_in, const int* in_sizes, int n_in,
                              void* d_out, int out_size, void* d_ws, size_t ws_size,
                              hipStream_t stream)
{
    (void)in_sizes; (void)n_in; (void)out_size; (void)ws_size;
    const float* input = (const float*)d_in[0];
    const float* Wih[4]; const float* Whh[4]; const float* Bih[4]; const float* Bhh[4];
    for (int i = 0; i < 4; ++i) {
        Wih[i] = (const float*)d_in[1 + 4 * i];
        Whh[i] = (const float*)d_in[2 + 4 * i];
        Bih[i] = (const float*)d_in[3 + 4 * i];
        Bhh[i] = (const float*)d_in[4 + 4 * i];
    }
    const float* mlpw = (const float*)d_in[17];
    const float* mlpb = (const float*)d_in[18];
    const float* adpw = (const float*)d_in[19];
    const float* adpb = (const float*)d_in[20];
    float* out = (float*)d_out;

    char* ws = (char*)d_ws;
    size_t off = 0;
    auto alloc = [&](size_t bytes) -> char* {
        char* ptr = ws + off;
        off += (bytes + 255) & ~(size_t)255;
        return ptr;
    };
    const size_t SEQB = (size_t)32768 * 512 * 2;   // 33.5 MB per hX buffer
    const size_t SYNC_BYTES = (size_t)(4096 + 4 * 16384) * 4;
    unsigned* syncc   = (unsigned*)alloc(SYNC_BYTES);
    _Float16* seqX    = (_Float16*)alloc((size_t)32768 * 128 * 2);
    _Float16* seq0X   = (_Float16*)alloc(SEQB);
    _Float16* seq1X   = (_Float16*)alloc(SEQB);
    _Float16* seq2X   = (_Float16*)alloc(SEQB);
    _Float16* seq3X   = (_Float16*)alloc(SEQB);
    _Float16* Wprep   = (_Float16*)alloc((size_t)2048 * 3712 * 2);
    float*    biasSum = (float*)alloc(8192 * 4);
    _Float16* mlpW16  = (_Float16*)alloc((size_t)262144 * 2);
    _Float16* adpW16  = (_Float16*)alloc((size_t)24576 * 2);

    hipMemsetAsync(syncc, 0, SYNC_BYTES, stream);
    prep_conv<<<2048, 256, 0, stream>>>(input, mlpw, adpw, seqX, mlpW16, adpW16);
    prep_bias<<<32, 256, 0, stream>>>(Bih[0], Bhh[0], Bih[1], Bhh[1],
                                      Bih[2], Bhh[2], Bih[3], Bhh[3], biasSum);
    prep_w<<<4096, 256, 0, stream>>>(Wih[0], Whh[0], Wih[1], Whh[1],
                                     Wih[2], Whh[2], Wih[3], Whh[3], Wprep);

    const int ldsBytes = MISC_OFF + 128;   // 151,680
    hipFuncSetAttribute((const void*)drnn_persist,
                        hipFuncAttributeMaxDynamicSharedMemorySize, ldsBytes);
    hipFuncSetAttribute((const void*)head_kernel,
                        hipFuncAttributeMaxDynamicSharedMemorySize, 65536);

    drnn_persist<<<256, TPB, ldsBytes, stream>>>(seqX, seq0X, seq1X, seq2X, seq3X,
                                                 Wprep, biasSum, syncc);
    head_kernel<<<512, 256, 65536, stream>>>(seq1X, seq3X, mlpW16, mlpb, adpW16, adpb, out);
}